// Round 1
// baseline (11991.766 us; speedup 1.0000x reference)
//
#include <hip/hip_runtime.h>
#include <hip/hip_fp16.h>

// Problem constants
#define BATCH 64
#define NBINS 64
#define TLEN  256
#define HD    512
#define G3    1536          // 3*H
#define KIN0  192           // folded conv+proj K = 64 bins * 3 taps
#define XT_S  258           // padded time slots (t' = -1 .. 256)
#define XT_STRIDE (XT_S*64) // per-batch stride in xT (16512)

typedef _Float16 f16;
typedef __attribute__((ext_vector_type(8))) _Float16 half8;
typedef __attribute__((ext_vector_type(4))) float    f32x4;

__device__ __forceinline__ f32x4 mfma16(half8 a, half8 b, f32x4 c) {
    return __builtin_amdgcn_mfma_f32_16x16x32_f16(a, b, c, 0, 0, 0);
}

// ---------------- setup kernels (run every call; cheap) ----------------

// W3[g, dt*64+i] = sum_{dr, r=i-dr in [0,62)} sum_f w_ih0[g, f*62+r] * cw[f,dr,dt]
__global__ void fold_w3(const float* __restrict__ wih0,
                        const float* __restrict__ convw,
                        f16* __restrict__ w3) {
    int idx = blockIdx.x * 256 + threadIdx.x;
    if (idx >= G3 * KIN0) return;
    int g  = idx / KIN0;
    int kk = idx % KIN0;
    int dt = kk >> 6;
    int i  = kk & 63;
    float s = 0.f;
    for (int dr = 0; dr < 3; ++dr) {
        int r = i - dr;
        if (r < 0 || r >= 62) continue;
        const float* wrow = wih0 + (size_t)g * 3968 + r;
        #pragma unroll 8
        for (int f = 0; f < 64; ++f)
            s += wrow[f * 62] * convw[f * 9 + dr * 3 + dt];
    }
    w3[(size_t)g * KIN0 + kk] = (f16)s;
}

// bias0[g] = b_ih0[g] + sum_f conv_b[f] * sum_{r<62} w_ih0[g, f*62+r]
__global__ void fold_bias0(const float* __restrict__ wih0,
                           const float* __restrict__ convb,
                           const float* __restrict__ bih0,
                           float* __restrict__ bias0) {
    int g = blockIdx.x * 256 + threadIdx.x;
    if (g >= G3) return;
    float s = bih0[g];
    for (int f = 0; f < 64; ++f) {
        const float* wrow = wih0 + (size_t)g * 3968 + f * 62;
        float acc = 0.f;
        #pragma unroll 31
        for (int r = 0; r < 62; ++r) acc += wrow[r];
        s += acc * convb[f];
    }
    bias0[g] = s;
}

struct Ptr5 { const float* p[5]; };

__global__ void cvt_weights(Ptr5 src, f16* __restrict__ dst) {
    int idx = blockIdx.x * 256 + threadIdx.x;
    if (idx >= 5 * G3 * HD) return;
    int m = idx / (G3 * HD), off = idx % (G3 * HD);
    dst[idx] = (f16)src.p[m][off];
}

// xT[b][s][i] = x[b, i, s-1] with zero pad at s=0 and s=257
__global__ void build_xt(const float* __restrict__ x, f16* __restrict__ xt) {
    int idx = blockIdx.x * 256 + threadIdx.x;
    if (idx >= BATCH * XT_S * 64) return;
    int b = idx / (XT_S * 64);
    int rem = idx % (XT_S * 64);
    int s = rem / 64, i = rem & 63;
    float v = 0.f;
    if (s >= 1 && s <= 256) v = x[(size_t)b * (64 * TLEN) + (size_t)i * TLEN + (s - 1)];
    xt[idx] = (f16)v;
}

__global__ void init_h(const float* __restrict__ h1, const float* __restrict__ h2,
                       const float* __restrict__ h3, f16* __restrict__ hbuf) {
    int idx = blockIdx.x * 256 + threadIdx.x;
    if (idx >= BATCH * HD) return;
    hbuf[idx]                 = (f16)h1[idx];
    hbuf[2 * BATCH * HD + idx] = (f16)h2[idx];
    hbuf[4 * BATCH * HD + idx] = (f16)h3[idx];
}

// ---------------- per-step GRU layer phase ----------------
// Grid: 32 blocks (each owns j-slice of 16 H-cols), 256 threads (4 waves,
// each wave one 16-row batch strip). GEMM via mfma_f32_16x16x32_f16 with
// direct global->VGPR fragment loads; GRU update fused in the epilogue.

template <int LAYER>
__global__ __launch_bounds__(256) void gru_phase(
    const f16* __restrict__ xin,   // LAYER==0: xT base; else c_in [64][512]
    const f16* __restrict__ hold,  // own previous state [64][512]
    const f16* __restrict__ wih,   // LAYER==0: W3 [1536][192]; else [1536][512]
    const f16* __restrict__ whh,   // [1536][512]
    const float* __restrict__ bih, // 1536 (LAYER==0: bias0 incl conv fold)
    const float* __restrict__ bhh, // 1536
    f16* __restrict__ hnew,        // [64][512]
    float* __restrict__ outp,      // LAYER==2: d_out + t*B*H
    int t)
{
    const int lane = threadIdx.x & 63;
    const int wid  = threadIdx.x >> 6;
    const int b0   = wid * 16;        // batch strip
    const int jc   = lane & 15;       // col-in-tile (also A row-in-tile)
    const int kg   = lane >> 4;       // k-group 0..3
    const int j0   = blockIdx.x * 16; // H slice
    const int j    = j0 + jc;

    constexpr int KIN = (LAYER == 0) ? KIN0 : HD;

    f32x4 accR  = {0.f, 0.f, 0.f, 0.f};
    f32x4 accZ  = {0.f, 0.f, 0.f, 0.f};
    f32x4 accNi = {0.f, 0.f, 0.f, 0.f};
    f32x4 accNh = {0.f, 0.f, 0.f, 0.f};

    const f16* wR = wih + (size_t)j * KIN;
    const f16* wZ = wih + (size_t)(HD + j) * KIN;
    const f16* wN = wih + (size_t)(2 * HD + j) * KIN;

    // ---- input-side GEMM: accR/accZ/accNi ----
    if (LAYER == 0) {
        const f16* xb = xin + (size_t)(b0 + jc) * XT_STRIDE + (size_t)t * 64;
        #pragma unroll
        for (int ks = 0; ks < KIN0 / 32; ++ks) {
            int off = ks * 32 + kg * 8;   // = dt*64 + i, 8 contiguous, never crosses dt
            half8 a  = *(const half8*)(xb + off);
            half8 br = *(const half8*)(wR + off);
            half8 bz = *(const half8*)(wZ + off);
            half8 bn = *(const half8*)(wN + off);
            accR  = mfma16(a, br, accR);
            accZ  = mfma16(a, bz, accZ);
            accNi = mfma16(a, bn, accNi);
        }
    } else {
        const f16* xb = xin + (size_t)(b0 + jc) * HD;
        #pragma unroll
        for (int ks = 0; ks < HD / 32; ++ks) {
            int off = ks * 32 + kg * 8;
            half8 a  = *(const half8*)(xb + off);
            half8 br = *(const half8*)(wR + off);
            half8 bz = *(const half8*)(wZ + off);
            half8 bn = *(const half8*)(wN + off);
            accR  = mfma16(a, br, accR);
            accZ  = mfma16(a, bz, accZ);
            accNi = mfma16(a, bn, accNi);
        }
    }

    // ---- hidden-side GEMM: accR/accZ/accNh ----
    {
        const f16* hb = hold + (size_t)(b0 + jc) * HD;
        const f16* vR = whh + (size_t)j * HD;
        const f16* vZ = whh + (size_t)(HD + j) * HD;
        const f16* vN = whh + (size_t)(2 * HD + j) * HD;
        #pragma unroll
        for (int ks = 0; ks < HD / 32; ++ks) {
            int off = ks * 32 + kg * 8;
            half8 a  = *(const half8*)(hb + off);
            half8 br = *(const half8*)(vR + off);
            half8 bz = *(const half8*)(vZ + off);
            half8 bn = *(const half8*)(vN + off);
            accR  = mfma16(a, br, accR);
            accZ  = mfma16(a, bz, accZ);
            accNh = mfma16(a, bn, accNh);
        }
    }

    // ---- fused GRU update epilogue ----
    const float bir = bih[j],          bhr = bhh[j];
    const float biz = bih[HD + j],     bhz = bhh[HD + j];
    const float bin = bih[2 * HD + j], bhn = bhh[2 * HD + j];

    #pragma unroll
    for (int rr = 0; rr < 4; ++rr) {
        int b = b0 + kg * 4 + rr;      // C/D row = (lane>>4)*4 + reg
        float r = 1.f / (1.f + __expf(-(accR[rr] + bir + bhr)));
        float z = 1.f / (1.f + __expf(-(accZ[rr] + biz + bhz)));
        float nv = accNi[rr] + bin + r * (accNh[rr] + bhn);
        float e  = __expf(2.f * nv);
        float n  = 1.f - 2.f / (e + 1.f);   // tanh, safe at +/-inf
        float ho = (float)hold[(size_t)b * HD + j];
        float hv = (1.f - z) * n + z * ho;
        hnew[(size_t)b * HD + j] = (f16)hv;
        if (LAYER == 2) outp[(size_t)b * HD + j] = hv;
    }
}

// ---------------- launch ----------------

extern "C" void kernel_launch(void* const* d_in, const int* in_sizes, int n_in,
                              void* d_out, int out_size, void* d_ws, size_t ws_size,
                              hipStream_t stream) {
    const float* x     = (const float*)d_in[0];
    const float* h1    = (const float*)d_in[1];
    const float* h2    = (const float*)d_in[2];
    const float* h3    = (const float*)d_in[3];
    const float* convw = (const float*)d_in[4];
    const float* convb = (const float*)d_in[5];
    const float* wih0  = (const float*)d_in[6];
    const float* whh0  = (const float*)d_in[7];
    const float* bih0  = (const float*)d_in[8];
    const float* bhh0  = (const float*)d_in[9];
    const float* wih1  = (const float*)d_in[10];
    const float* whh1  = (const float*)d_in[11];
    const float* bih1  = (const float*)d_in[12];
    const float* bhh1  = (const float*)d_in[13];
    const float* wih2  = (const float*)d_in[14];
    const float* whh2  = (const float*)d_in[15];
    const float* bih2  = (const float*)d_in[16];
    const float* bhh2  = (const float*)d_in[17];

    // workspace layout (all 16B-aligned); total ~11 MB
    char* ws = (char*)d_ws;
    f16*   W3    = (f16*)(ws + 0);            // 1536*192*2      = 589824
    float* bias0 = (float*)(ws + 589824);     // 1536*4          = 6144
    f16*   wts   = (f16*)(ws + 595968);       // 5*1536*512*2    = 7864320
    f16*   xT    = (f16*)(ws + 8460288);      // 64*258*64*2     = 2113536
    f16*   hb    = (f16*)(ws + 10573824);     // 6*64*512*2      = 393216

    fold_w3   <<<(G3 * KIN0 + 255) / 256, 256, 0, stream>>>(wih0, convw, W3);
    fold_bias0<<<(G3 + 255) / 256,       256, 0, stream>>>(wih0, convb, bih0, bias0);
    Ptr5 p5; p5.p[0] = whh0; p5.p[1] = wih1; p5.p[2] = whh1; p5.p[3] = wih2; p5.p[4] = whh2;
    cvt_weights<<<(5 * G3 * HD + 255) / 256, 256, 0, stream>>>(p5, wts);
    build_xt  <<<(BATCH * XT_S * 64 + 255) / 256, 256, 0, stream>>>(x, xT);
    init_h    <<<(BATCH * HD + 255) / 256, 256, 0, stream>>>(h1, h2, h3, hb);

    f16* whh0h = wts + 0 * (size_t)(G3 * HD);
    f16* wih1h = wts + 1 * (size_t)(G3 * HD);
    f16* whh1h = wts + 2 * (size_t)(G3 * HD);
    f16* wih2h = wts + 3 * (size_t)(G3 * HD);
    f16* whh2h = wts + 4 * (size_t)(G3 * HD);

    const int HS = BATCH * HD; // 32768 elements per state buffer
    float* out = (float*)d_out;

    for (int t = 0; t < TLEN; ++t) {
        int pi = t & 1, po = (t + 1) & 1;
        f16* h1i = hb + 0 * HS + pi * HS;  f16* h1o = hb + 0 * HS + po * HS;
        f16* h2i = hb + 2 * HS + pi * HS;  f16* h2o = hb + 2 * HS + po * HS;
        f16* h3i = hb + 4 * HS + pi * HS;  f16* h3o = hb + 4 * HS + po * HS;

        gru_phase<0><<<32, 256, 0, stream>>>(xT,  h1i, W3,    whh0h, bias0, bhh0, h1o, nullptr, t);
        gru_phase<1><<<32, 256, 0, stream>>>(h1o, h2i, wih1h, whh1h, bih1,  bhh1, h2o, nullptr, t);
        gru_phase<2><<<32, 256, 0, stream>>>(h2o, h3i, wih2h, whh2h, bih2,  bhh2, h3o,
                                             out + (size_t)t * HS, t);
    }
}

// Round 2
// 4907.184 us; speedup vs baseline: 2.4437x; 2.4437x over previous
//
#include <hip/hip_runtime.h>
#include <hip/hip_fp16.h>

// Problem constants
#define BATCH 64
#define TLEN  256
#define HD    512
#define G3    1536          // 3*H
#define KIN0  192           // folded conv+proj K = 64 bins * 3 taps
#define XT_S  258           // padded time slots (t' = -1 .. 256)
#define XT_STRIDE (XT_S*64) // per-batch stride in xT (16512)
#define NBLOCKS 96
#define WSTRIDE 520         // padded LDS row stride in f16 (260 dwords -> bank+4/row)

typedef _Float16 f16;
typedef __attribute__((ext_vector_type(8))) _Float16 half8;
typedef __attribute__((ext_vector_type(4))) float    f32x4;

__device__ __forceinline__ f32x4 mfma16(half8 a, half8 b, f32x4 c) {
    return __builtin_amdgcn_mfma_f32_16x16x32_f16(a, b, c, 0, 0, 0);
}

// ---------------- setup kernels ----------------

__global__ void fold_w3(const float* __restrict__ wih0,
                        const float* __restrict__ convw,
                        f16* __restrict__ w3) {
    int idx = blockIdx.x * 256 + threadIdx.x;
    if (idx >= G3 * KIN0) return;
    int g  = idx / KIN0;
    int kk = idx % KIN0;
    int dt = kk >> 6;
    int i  = kk & 63;
    float s = 0.f;
    for (int dr = 0; dr < 3; ++dr) {
        int r = i - dr;
        if (r < 0 || r >= 62) continue;
        const float* wrow = wih0 + (size_t)g * 3968 + r;
        #pragma unroll 8
        for (int f = 0; f < 64; ++f)
            s += wrow[f * 62] * convw[f * 9 + dr * 3 + dt];
    }
    w3[(size_t)g * KIN0 + kk] = (f16)s;
}

__global__ void fold_bias0(const float* __restrict__ wih0,
                           const float* __restrict__ convb,
                           const float* __restrict__ bih0,
                           float* __restrict__ bias0) {
    int g = blockIdx.x * 256 + threadIdx.x;
    if (g >= G3) return;
    float s = bih0[g];
    for (int f = 0; f < 64; ++f) {
        const float* wrow = wih0 + (size_t)g * 3968 + f * 62;
        float acc = 0.f;
        #pragma unroll 31
        for (int r = 0; r < 62; ++r) acc += wrow[r];
        s += acc * convb[f];
    }
    bias0[g] = s;
}

struct Ptr5 { const float* p[5]; };

__global__ void cvt_weights(Ptr5 src, f16* __restrict__ dst) {
    int idx = blockIdx.x * 256 + threadIdx.x;
    if (idx >= 5 * G3 * HD) return;
    int m = idx / (G3 * HD), off = idx % (G3 * HD);
    dst[idx] = (f16)src.p[m][off];
}

// xT[b][s][i] = x[b, i, s-1] with zero pad at s=0 and s=257
__global__ void build_xt(const float* __restrict__ x, f16* __restrict__ xt) {
    int idx = blockIdx.x * 256 + threadIdx.x;
    if (idx >= BATCH * XT_S * 64) return;
    int b = idx / (XT_S * 64);
    int rem = idx % (XT_S * 64);
    int s = rem / 64, i = rem & 63;
    float v = 0.f;
    if (s >= 1 && s <= 256) v = x[(size_t)b * (64 * TLEN) + (size_t)i * TLEN + (s - 1)];
    xt[idx] = (f16)v;
}

// h(-1) lives at parity slot 1; also zero the grid-barrier words.
__global__ void init_h(const float* __restrict__ h1, const float* __restrict__ h2,
                       const float* __restrict__ h3, f16* __restrict__ hbuf,
                       unsigned* __restrict__ bar) {
    int idx = blockIdx.x * 256 + threadIdx.x;
    const int HS = BATCH * HD;
    if (idx < 2) bar[idx] = 0u;
    if (idx >= HS) return;
    hbuf[1 * HS + idx] = (f16)h1[idx];
    hbuf[3 * HS + idx] = (f16)h2[idx];
    hbuf[5 * HS + idx] = (f16)h3[idx];
}

// ---------------- persistent diagonal-pipelined GRU ----------------

__device__ __forceinline__ void grid_barrier(unsigned* bar) {
    __syncthreads();
    if (threadIdx.x == 0) {
        __threadfence();  // agent-scope release of this block's writes
        unsigned g = __hip_atomic_load(&bar[1], __ATOMIC_RELAXED, __HIP_MEMORY_SCOPE_AGENT);
        unsigned arrived = __hip_atomic_fetch_add(&bar[0], 1u, __ATOMIC_ACQ_REL, __HIP_MEMORY_SCOPE_AGENT);
        if (arrived == NBLOCKS - 1) {
            __hip_atomic_store(&bar[0], 0u, __ATOMIC_RELAXED, __HIP_MEMORY_SCOPE_AGENT);
            __hip_atomic_fetch_add(&bar[1], 1u, __ATOMIC_RELEASE, __HIP_MEMORY_SCOPE_AGENT);
        } else {
            while (__hip_atomic_load(&bar[1], __ATOMIC_ACQUIRE, __HIP_MEMORY_SCOPE_AGENT) == g)
                __builtin_amdgcn_s_sleep(1);
        }
    }
    __syncthreads();
}

__global__ __launch_bounds__(256, 1) void gru_persistent(
    const f16* __restrict__ xT, const f16* __restrict__ W3,
    const f16* __restrict__ wts,
    const float* __restrict__ bias0, const float* __restrict__ bhh0,
    const float* __restrict__ bih1,  const float* __restrict__ bhh1,
    const float* __restrict__ bih2,  const float* __restrict__ bhh2,
    f16* __restrict__ hb, float* __restrict__ out, unsigned* __restrict__ bar)
{
    __shared__ f16 wih_lds[48 * WSTRIDE];
    __shared__ f16 whh_lds[48 * WSTRIDE];

    const int bid   = blockIdx.x;
    const int layer = bid >> 5;       // 0..2
    const int slice = bid & 31;       // 0..31
    const int j0    = slice * 16;
    const int tid   = threadIdx.x;
    const int lane  = tid & 63;
    const int wid   = tid >> 6;
    const int b0    = wid * 16;
    const int jc    = lane & 15;
    const int kg    = lane >> 4;
    const int j     = j0 + jc;

    const int KIN = (layer == 0) ? KIN0 : HD;
    const f16* wih_g = (layer == 0) ? W3 : (wts + (size_t)(2 * layer - 1) * (G3 * HD));
    const f16* whh_g = wts + (size_t)(2 * layer) * (G3 * HD);

    // ---- stage weight slices into LDS (once) ----
    for (int e = tid; e < 48 * (KIN / 8); e += 256) {
        int r = e / (KIN / 8), c = (e % (KIN / 8)) * 8;
        int gate = r >> 4, jr = j0 + (r & 15);
        *(half8*)(&wih_lds[r * WSTRIDE + c]) =
            *(const half8*)(wih_g + (size_t)(gate * HD + jr) * KIN + c);
    }
    for (int e = tid; e < 48 * 64; e += 256) {
        int r = e / 64, c = (e % 64) * 8;
        int gate = r >> 4, jr = j0 + (r & 15);
        *(half8*)(&whh_lds[r * WSTRIDE + c]) =
            *(const half8*)(whh_g + (size_t)(gate * HD + jr) * HD + c);
    }

    const float* bih = (layer == 0) ? bias0 : ((layer == 1) ? bih1 : bih2);
    const float* bhh = (layer == 0) ? bhh0  : ((layer == 1) ? bhh1 : bhh2);
    const float bir = bih[j],          bhr = bhh[j];
    const float biz = bih[HD + j],     bhz = bhh[HD + j];
    const float bin = bih[2 * HD + j], bhn = bhh[2 * HD + j];

    __syncthreads();

    const int HS = BATCH * HD;
    f16* hbase = hb + (size_t)layer * 2 * HS;
    const f16* hprev_base = (layer == 0) ? nullptr : (hb + (size_t)(layer - 1) * 2 * HS);

    for (int R = 0; R < XT_S; ++R) {
        const int t = R - layer;
        if (t >= 0 && t < TLEN) {
            const f16* hold = hbase + (((t - 1) & 1)) * HS;
            f16*       hnew = hbase + ((t & 1)) * HS;

            f32x4 accR  = {0.f, 0.f, 0.f, 0.f};
            f32x4 accZ  = {0.f, 0.f, 0.f, 0.f};
            f32x4 accNi = {0.f, 0.f, 0.f, 0.f};
            f32x4 accNh = {0.f, 0.f, 0.f, 0.f};

            const f16* wR = &wih_lds[(0 * 16 + jc) * WSTRIDE];
            const f16* wZ = &wih_lds[(1 * 16 + jc) * WSTRIDE];
            const f16* wN = &wih_lds[(2 * 16 + jc) * WSTRIDE];

            if (layer == 0) {
                const f16* xb = xT + (size_t)(b0 + jc) * XT_STRIDE + (size_t)t * 64;
                #pragma unroll
                for (int ks = 0; ks < KIN0 / 32; ++ks) {
                    int off = ks * 32 + kg * 8;
                    half8 a  = *(const half8*)(xb + off);
                    accR  = mfma16(a, *(const half8*)(wR + off), accR);
                    accZ  = mfma16(a, *(const half8*)(wZ + off), accZ);
                    accNi = mfma16(a, *(const half8*)(wN + off), accNi);
                }
            } else {
                const f16* xb = hprev_base + ((t & 1)) * HS + (size_t)(b0 + jc) * HD;
                #pragma unroll
                for (int ks = 0; ks < HD / 32; ++ks) {
                    int off = ks * 32 + kg * 8;
                    half8 a  = *(const half8*)(xb + off);
                    accR  = mfma16(a, *(const half8*)(wR + off), accR);
                    accZ  = mfma16(a, *(const half8*)(wZ + off), accZ);
                    accNi = mfma16(a, *(const half8*)(wN + off), accNi);
                }
            }

            {
                const f16* hbp = hold + (size_t)(b0 + jc) * HD;
                const f16* vR = &whh_lds[(0 * 16 + jc) * WSTRIDE];
                const f16* vZ = &whh_lds[(1 * 16 + jc) * WSTRIDE];
                const f16* vN = &whh_lds[(2 * 16 + jc) * WSTRIDE];
                #pragma unroll
                for (int ks = 0; ks < HD / 32; ++ks) {
                    int off = ks * 32 + kg * 8;
                    half8 a  = *(const half8*)(hbp + off);
                    accR  = mfma16(a, *(const half8*)(vR + off), accR);
                    accZ  = mfma16(a, *(const half8*)(vZ + off), accZ);
                    accNh = mfma16(a, *(const half8*)(vN + off), accNh);
                }
            }

            #pragma unroll
            for (int rr = 0; rr < 4; ++rr) {
                int b = b0 + kg * 4 + rr;   // C/D row = (lane>>4)*4 + reg
                float r = 1.f / (1.f + __expf(-(accR[rr] + bir + bhr)));
                float z = 1.f / (1.f + __expf(-(accZ[rr] + biz + bhz)));
                float nv = accNi[rr] + bin + r * (accNh[rr] + bhn);
                float e  = __expf(2.f * nv);
                float n  = 1.f - 2.f / (e + 1.f);   // tanh, safe at +/-inf
                float ho = (float)hold[(size_t)b * HD + j];
                float hv = (1.f - z) * n + z * ho;
                hnew[(size_t)b * HD + j] = (f16)hv;
                if (layer == 2) out[(size_t)t * HS + (size_t)b * HD + j] = hv;
            }
        }
        if (R < XT_S - 1) grid_barrier(bar);
    }
}

// ---------------- launch ----------------

extern "C" void kernel_launch(void* const* d_in, const int* in_sizes, int n_in,
                              void* d_out, int out_size, void* d_ws, size_t ws_size,
                              hipStream_t stream) {
    const float* x     = (const float*)d_in[0];
    const float* h1    = (const float*)d_in[1];
    const float* h2    = (const float*)d_in[2];
    const float* h3    = (const float*)d_in[3];
    const float* convw = (const float*)d_in[4];
    const float* convb = (const float*)d_in[5];
    const float* wih0  = (const float*)d_in[6];
    const float* bih0  = (const float*)d_in[8];
    const float* bhh0  = (const float*)d_in[9];
    const float* wih1  = (const float*)d_in[10];
    const float* whh0  = (const float*)d_in[7];
    const float* whh1  = (const float*)d_in[11];
    const float* bih1  = (const float*)d_in[12];
    const float* bhh1  = (const float*)d_in[13];
    const float* wih2  = (const float*)d_in[14];
    const float* whh2  = (const float*)d_in[15];
    const float* bih2  = (const float*)d_in[16];
    const float* bhh2  = (const float*)d_in[17];

    // workspace layout (16B-aligned)
    char* ws = (char*)d_ws;
    unsigned* bar  = (unsigned*)(ws + 0);      // 64 B
    f16*   W3    = (f16*)(ws + 64);            // 1536*192*2      = 589824
    float* bias0 = (float*)(ws + 589888);      // 1536*4          = 6144
    f16*   wts   = (f16*)(ws + 596032);        // 5*1536*512*2    = 7864320
    f16*   xT    = (f16*)(ws + 8460352);       // 64*258*64*2     = 2113536
    f16*   hb    = (f16*)(ws + 10573888);      // 6*64*512*2      = 393216

    fold_w3   <<<(G3 * KIN0 + 255) / 256, 256, 0, stream>>>(wih0, convw, W3);
    fold_bias0<<<(G3 + 255) / 256,       256, 0, stream>>>(wih0, convb, bih0, bias0);
    Ptr5 p5; p5.p[0] = whh0; p5.p[1] = wih1; p5.p[2] = whh1; p5.p[3] = wih2; p5.p[4] = whh2;
    cvt_weights<<<(5 * G3 * HD + 255) / 256, 256, 0, stream>>>(p5, wts);
    build_xt  <<<(BATCH * XT_S * 64 + 255) / 256, 256, 0, stream>>>(x, xT);
    init_h    <<<(BATCH * HD + 255) / 256, 256, 0, stream>>>(h1, h2, h3, hb, bar);

    gru_persistent<<<NBLOCKS, 256, 0, stream>>>(
        xT, W3, wts, bias0, bhh0, bih1, bhh1, bih2, bhh2,
        hb, (float*)d_out, bar);
}

// Round 3
// 2958.186 us; speedup vs baseline: 4.0538x; 1.6588x over previous
//
#include <hip/hip_runtime.h>
#include <hip/hip_fp16.h>

// Problem constants
#define BATCH 64
#define TLEN  256
#define HD    512
#define G3    1536          // 3*H
#define KIN0  192           // folded conv+proj K = 64 bins * 3 taps
#define XT_S  258           // padded time slots (t' = -1 .. 256)
#define XT_STRIDE (XT_S*64) // per-batch stride in xT (16512)
#define NBLOCKS 96
#define WSTRIDE 520         // padded LDS row stride in f16

typedef _Float16 f16;
typedef unsigned long long u64;
typedef __attribute__((ext_vector_type(8))) _Float16 half8;
typedef __attribute__((ext_vector_type(4))) float    f32x4;

__device__ __forceinline__ f32x4 mfma16(half8 a, half8 b, f32x4 c) {
    return __builtin_amdgcn_mfma_f32_16x16x32_f16(a, b, c, 0, 0, 0);
}

// Device-coherent (MALL) 16B load as two relaxed agent-scope u64 atomic loads.
// Relaxed agent atomics compile to global_load_dwordx2 ... sc1 (no fences).
__device__ __forceinline__ half8 loadA_sc1(const f16* p) {
    union { u64 v[2]; half8 h; } u;
    const u64* q = (const u64*)p;
    u.v[0] = __hip_atomic_load(q,     __ATOMIC_RELAXED, __HIP_MEMORY_SCOPE_AGENT);
    u.v[1] = __hip_atomic_load(q + 1, __ATOMIC_RELAXED, __HIP_MEMORY_SCOPE_AGENT);
    return u.h;
}

// ---------------- setup kernels ----------------

__global__ void fold_w3(const float* __restrict__ wih0,
                        const float* __restrict__ convw,
                        f16* __restrict__ w3) {
    int idx = blockIdx.x * 256 + threadIdx.x;
    if (idx >= G3 * KIN0) return;
    int g  = idx / KIN0;
    int kk = idx % KIN0;
    int dt = kk >> 6;
    int i  = kk & 63;
    float s = 0.f;
    for (int dr = 0; dr < 3; ++dr) {
        int r = i - dr;
        if (r < 0 || r >= 62) continue;
        const float* wrow = wih0 + (size_t)g * 3968 + r;
        #pragma unroll 8
        for (int f = 0; f < 64; ++f)
            s += wrow[f * 62] * convw[f * 9 + dr * 3 + dt];
    }
    w3[(size_t)g * KIN0 + kk] = (f16)s;
}

// wave-per-row: bias0[g] = b_ih0[g] + sum_e wih0[g,e] * convb[e/62]
__global__ void fold_bias0(const float* __restrict__ wih0,
                           const float* __restrict__ convb,
                           const float* __restrict__ bih0,
                           float* __restrict__ bias0) {
    int w    = (blockIdx.x * 256 + threadIdx.x) >> 6;
    int lane = threadIdx.x & 63;
    if (w >= G3) return;
    const float* wrow = wih0 + (size_t)w * 3968;
    float s = 0.f;
    for (int e = lane; e < 3968; e += 64) s += wrow[e] * convb[e / 62];
    #pragma unroll
    for (int o = 32; o > 0; o >>= 1) s += __shfl_down(s, o);
    if (lane == 0) bias0[w] = s + bih0[w];
}

struct Ptr5 { const float* p[5]; };

__global__ void cvt_weights(Ptr5 src, f16* __restrict__ dst) {
    int idx = blockIdx.x * 256 + threadIdx.x;
    if (idx >= 5 * G3 * HD) return;
    int m = idx / (G3 * HD), off = idx % (G3 * HD);
    dst[idx] = (f16)src.p[m][off];
}

// xT[b][s][i] = x[b, i, s-1] with zero pad at s=0 and s=257
__global__ void build_xt(const float* __restrict__ x, f16* __restrict__ xt) {
    int idx = blockIdx.x * 256 + threadIdx.x;
    if (idx >= BATCH * XT_S * 64) return;
    int b = idx / (XT_S * 64);
    int rem = idx % (XT_S * 64);
    int s = rem / 64, i = rem & 63;
    float v = 0.f;
    if (s >= 1 && s <= 256) v = x[(size_t)b * (64 * TLEN) + (size_t)i * TLEN + (s - 1)];
    xt[idx] = (f16)v;
}

// h(-1) lives at parity slot 1; also zero the grid-barrier counter.
__global__ void init_h(const float* __restrict__ h1, const float* __restrict__ h2,
                       const float* __restrict__ h3, f16* __restrict__ hbuf,
                       unsigned* __restrict__ bar) {
    int idx = blockIdx.x * 256 + threadIdx.x;
    const int HS = BATCH * HD;
    if (idx < 16) bar[idx] = 0u;
    if (idx >= HS) return;
    hbuf[1 * HS + idx] = (f16)h1[idx];
    hbuf[3 * HS + idx] = (f16)h2[idx];
    hbuf[5 * HS + idx] = (f16)h3[idx];
}

// ---------------- persistent diagonal-pipelined GRU ----------------
// Fence-free grid barrier: monotone counter at the MALL. __syncthreads()
// drains each wave's sc1 stores (s_waitcnt vmcnt(0) before s_barrier), so
// when the counter reaches target, all round-R data is at the coherence
// point; subsequent sc1 loads read it directly. No wbl2 / buffer_inv.
__device__ __forceinline__ void grid_barrier(unsigned* bar, unsigned target) {
    __syncthreads();
    if (threadIdx.x == 0) {
        __hip_atomic_fetch_add(&bar[0], 1u, __ATOMIC_RELAXED, __HIP_MEMORY_SCOPE_AGENT);
        while (__hip_atomic_load(&bar[0], __ATOMIC_RELAXED, __HIP_MEMORY_SCOPE_AGENT) < target)
            __builtin_amdgcn_s_sleep(1);
        asm volatile("" ::: "memory");
    }
    __syncthreads();
}

__global__ __launch_bounds__(256, 1) void gru_persistent(
    const f16* __restrict__ xT, const f16* __restrict__ W3,
    const f16* __restrict__ wts,
    const float* __restrict__ bias0, const float* __restrict__ bhh0,
    const float* __restrict__ bih1,  const float* __restrict__ bhh1,
    const float* __restrict__ bih2,  const float* __restrict__ bhh2,
    f16* __restrict__ hb, float* __restrict__ out, unsigned* __restrict__ bar)
{
    __shared__ f16 wih_lds[48 * WSTRIDE];
    __shared__ f16 whh_lds[48 * WSTRIDE];

    const int bid   = blockIdx.x;
    const int layer = bid >> 5;       // 0..2
    const int slice = bid & 31;       // 0..31
    const int j0    = slice * 16;
    const int tid   = threadIdx.x;
    const int lane  = tid & 63;
    const int wid   = tid >> 6;
    const int b0    = wid * 16;
    const int jc    = lane & 15;
    const int kg    = lane >> 4;
    const int j     = j0 + jc;

    const int KIN = (layer == 0) ? KIN0 : HD;
    const f16* wih_g = (layer == 0) ? W3 : (wts + (size_t)(2 * layer - 1) * (G3 * HD));
    const f16* whh_g = wts + (size_t)(2 * layer) * (G3 * HD);

    // ---- stage weight slices into LDS (once) ----
    for (int e = tid; e < 48 * (KIN / 8); e += 256) {
        int r = e / (KIN / 8), c = (e % (KIN / 8)) * 8;
        int gate = r >> 4, jr = j0 + (r & 15);
        *(half8*)(&wih_lds[r * WSTRIDE + c]) =
            *(const half8*)(wih_g + (size_t)(gate * HD + jr) * KIN + c);
    }
    for (int e = tid; e < 48 * 64; e += 256) {
        int r = e / 64, c = (e % 64) * 8;
        int gate = r >> 4, jr = j0 + (r & 15);
        *(half8*)(&whh_lds[r * WSTRIDE + c]) =
            *(const half8*)(whh_g + (size_t)(gate * HD + jr) * HD + c);
    }

    const float* bih = (layer == 0) ? bias0 : ((layer == 1) ? bih1 : bih2);
    const float* bhh = (layer == 0) ? bhh0  : ((layer == 1) ? bhh1 : bhh2);
    const float bir = bih[j],          bhr = bhh[j];
    const float biz = bih[HD + j],     bhz = bhh[HD + j];
    const float bin = bih[2 * HD + j], bhn = bhh[2 * HD + j];

    const int HS = BATCH * HD;
    f16* hbase = hb + (size_t)layer * 2 * HS;
    const f16* hprev_base = (layer == 0) ? nullptr : (hb + (size_t)(layer - 1) * 2 * HS);

    // previous own-h for the z-blend, carried in registers (this thread wrote
    // exactly these (b,j) elements last round)
    float hpr[4];
    {
        const f16* hinit = hbase + 1 * HS;   // parity of t = -1
        #pragma unroll
        for (int rr = 0; rr < 4; ++rr)
            hpr[rr] = (float)hinit[(size_t)(b0 + kg * 4 + rr) * HD + j];
    }

    __syncthreads();

    const f16* wR = &wih_lds[(0 * 16 + jc) * WSTRIDE];
    const f16* wZ = &wih_lds[(1 * 16 + jc) * WSTRIDE];
    const f16* wN = &wih_lds[(2 * 16 + jc) * WSTRIDE];
    const f16* vR = &whh_lds[(0 * 16 + jc) * WSTRIDE];
    const f16* vZ = &whh_lds[(1 * 16 + jc) * WSTRIDE];
    const f16* vN = &whh_lds[(2 * 16 + jc) * WSTRIDE];

    for (int R = 0; R < XT_S; ++R) {
        const int t = R - layer;
        if (t >= 0 && t < TLEN) {
            f16* hnew = hbase + ((t & 1)) * HS;
            const f16* hold = hbase + (((t - 1) & 1)) * HS;

            f32x4 accR  = {0.f, 0.f, 0.f, 0.f};
            f32x4 accZ  = {0.f, 0.f, 0.f, 0.f};
            f32x4 accNi = {0.f, 0.f, 0.f, 0.f};
            f32x4 accNh = {0.f, 0.f, 0.f, 0.f};

            const f16* hbp = hold + (size_t)(b0 + jc) * HD;

            if (layer == 0) {
                // hidden side (sc1, long latency) first; input side (L2) after
                #pragma unroll
                for (int ks = 0; ks < HD / 32; ++ks) {
                    int off = ks * 32 + kg * 8;
                    half8 aH = loadA_sc1(hbp + off);
                    accR  = mfma16(aH, *(const half8*)(vR + off), accR);
                    accZ  = mfma16(aH, *(const half8*)(vZ + off), accZ);
                    accNh = mfma16(aH, *(const half8*)(vN + off), accNh);
                }
                const f16* xb = xT + (size_t)(b0 + jc) * XT_STRIDE + (size_t)t * 64;
                #pragma unroll
                for (int ks = 0; ks < KIN0 / 32; ++ks) {
                    int off = ks * 32 + kg * 8;
                    half8 a = *(const half8*)(xb + off);
                    accR  = mfma16(a, *(const half8*)(wR + off), accR);
                    accZ  = mfma16(a, *(const half8*)(wZ + off), accZ);
                    accNi = mfma16(a, *(const half8*)(wN + off), accNi);
                }
            } else {
                const f16* xb = hprev_base + ((t & 1)) * HS + (size_t)(b0 + jc) * HD;
                #pragma unroll
                for (int ks = 0; ks < HD / 32; ++ks) {
                    int off = ks * 32 + kg * 8;
                    half8 aX = loadA_sc1(xb + off);
                    half8 aH = loadA_sc1(hbp + off);
                    accR  = mfma16(aX, *(const half8*)(wR + off), accR);
                    accZ  = mfma16(aX, *(const half8*)(wZ + off), accZ);
                    accNi = mfma16(aX, *(const half8*)(wN + off), accNi);
                    accR  = mfma16(aH, *(const half8*)(vR + off), accR);
                    accZ  = mfma16(aH, *(const half8*)(vZ + off), accZ);
                    accNh = mfma16(aH, *(const half8*)(vN + off), accNh);
                }
            }

            #pragma unroll
            for (int rr = 0; rr < 4; ++rr) {
                int brow = b0 + kg * 4 + rr;   // C/D row = (lane>>4)*4 + reg
                float r = 1.f / (1.f + __expf(-(accR[rr] + bir + bhr)));
                float z = 1.f / (1.f + __expf(-(accZ[rr] + biz + bhz)));
                float nv = accNi[rr] + bin + r * (accNh[rr] + bhn);
                float e  = __expf(2.f * nv);
                float n  = 1.f - 2.f / (e + 1.f);   // tanh, safe at +/-inf
                float hv = (1.f - z) * n + z * hpr[rr];
                hpr[rr] = hv;
                // pack (j, j+1) f16 pair; even-jc lanes store u32 sc1
                float nbv = __shfl_xor(hv, 1);
                if (!(jc & 1)) {
                    unsigned short ua = __builtin_bit_cast(unsigned short, (f16)hv);
                    unsigned short ub = __builtin_bit_cast(unsigned short, (f16)nbv);
                    unsigned pk = (unsigned)ua | ((unsigned)ub << 16);
                    __hip_atomic_store((unsigned*)(hnew + (size_t)brow * HD + j), pk,
                                       __ATOMIC_RELAXED, __HIP_MEMORY_SCOPE_AGENT);
                }
                if (layer == 2) out[(size_t)t * HS + (size_t)brow * HD + j] = hv;
            }
        }
        if (R < XT_S - 1) grid_barrier(bar, (unsigned)(R + 1) * NBLOCKS);
    }
}

// ---------------- launch ----------------

extern "C" void kernel_launch(void* const* d_in, const int* in_sizes, int n_in,
                              void* d_out, int out_size, void* d_ws, size_t ws_size,
                              hipStream_t stream) {
    const float* x     = (const float*)d_in[0];
    const float* h1    = (const float*)d_in[1];
    const float* h2    = (const float*)d_in[2];
    const float* h3    = (const float*)d_in[3];
    const float* convw = (const float*)d_in[4];
    const float* convb = (const float*)d_in[5];
    const float* wih0  = (const float*)d_in[6];
    const float* whh0  = (const float*)d_in[7];
    const float* bih0  = (const float*)d_in[8];
    const float* bhh0  = (const float*)d_in[9];
    const float* wih1  = (const float*)d_in[10];
    const float* whh1  = (const float*)d_in[11];
    const float* bih1  = (const float*)d_in[12];
    const float* bhh1  = (const float*)d_in[13];
    const float* wih2  = (const float*)d_in[14];
    const float* whh2  = (const float*)d_in[15];
    const float* bih2  = (const float*)d_in[16];
    const float* bhh2  = (const float*)d_in[17];

    // workspace layout (16B-aligned)
    char* ws = (char*)d_ws;
    unsigned* bar  = (unsigned*)(ws + 0);      // 64 B
    f16*   W3    = (f16*)(ws + 64);            // 1536*192*2      = 589824
    float* bias0 = (float*)(ws + 589888);      // 1536*4          = 6144
    f16*   wts   = (f16*)(ws + 596032);        // 5*1536*512*2    = 7864320
    f16*   xT    = (f16*)(ws + 8460352);       // 64*258*64*2     = 2113536
    f16*   hb    = (f16*)(ws + 10573888);      // 6*64*512*2      = 393216

    fold_w3   <<<(G3 * KIN0 + 255) / 256, 256, 0, stream>>>(wih0, convw, W3);
    fold_bias0<<<(G3 * 64 + 255) / 256,   256, 0, stream>>>(wih0, convb, bih0, bias0);
    Ptr5 p5; p5.p[0] = whh0; p5.p[1] = wih1; p5.p[2] = whh1; p5.p[3] = wih2; p5.p[4] = whh2;
    cvt_weights<<<(5 * G3 * HD + 255) / 256, 256, 0, stream>>>(p5, wts);
    build_xt  <<<(BATCH * XT_S * 64 + 255) / 256, 256, 0, stream>>>(x, xT);
    init_h    <<<(BATCH * HD + 255) / 256, 256, 0, stream>>>(h1, h2, h3, hb, bar);

    gru_persistent<<<NBLOCKS, 256, 0, stream>>>(
        xT, W3, wts, bias0, bhh0, bih1, bhh1, bih2, bhh2,
        hb, (float*)d_out, bar);
}